// Round 3
// baseline (718.857 us; speedup 1.0000x reference)
//
#include <hip/hip_runtime.h>

#define DIM   256
#define KCB   8192
#define NTOK  32768
#define NSPLIT 4
#define CPS   2048      // codes per split

using half8 = __attribute__((ext_vector_type(8))) _Float16;
using half4 = __attribute__((ext_vector_type(4))) _Float16;
using f32x4 = __attribute__((ext_vector_type(4))) float;

#define GLOBAL_AS(p) ((const __attribute__((address_space(1))) void*)(p))
#define LDS_AS(p)    ((__attribute__((address_space(3))) void*)(p))

__device__ __forceinline__ void ins2(float v, int i, float& b1v, int& b1i,
                                     float& b2v, int& b2i) {
    bool bet1 = (v < b1v) || (v == b1v && i < b1i);
    bool bet2 = (v < b2v) || (v == b2v && i < b2i);
    if (bet1) { b2v = b1v; b2i = b1i; b1v = v; b1i = i; }
    else if (bet2) { b2v = v; b2i = i; }
}

// ---------------- kernel: split fp32 rows into fp16 (hi, lo) [+ row norms] ----------------
__global__ __launch_bounds__(256) void k_split(const float* __restrict__ src,
                                               _Float16* __restrict__ hi,
                                               _Float16* __restrict__ lo,
                                               float* __restrict__ norm, int nrows) {
    int row = (int)((blockIdx.x * blockDim.x + threadIdx.x) >> 6);
    int lane = threadIdx.x & 63;
    if (row >= nrows) return;
    float4 v = *(const float4*)&src[(size_t)row * DIM + lane * 4];
    float vv[4] = {v.x, v.y, v.z, v.w};
    half4 hh, hl;
    #pragma unroll
    for (int j = 0; j < 4; ++j) {
        _Float16 h = (_Float16)vv[j];
        hh[j] = h;
        hl[j] = (_Float16)(vv[j] - (float)h);
    }
    *(half4*)&hi[(size_t)row * DIM + lane * 4] = hh;
    *(half4*)&lo[(size_t)row * DIM + lane * 4] = hl;
    if (norm) {
        float s = v.x*v.x + v.y*v.y + v.z*v.z + v.w*v.w;
        #pragma unroll
        for (int m = 32; m; m >>= 1) s += __shfl_xor(s, m);
        if (lane == 0) norm[row] = s;
    }
}

// ---------------- kernel: z = x @ W^T + b via fp16x3 MFMA, stored as (zh, zl) ----------------
// block = 64 tokens x 256 e; wave w covers e-range [w*64, w*64+64); no LDS, no barriers.
__global__ __launch_bounds__(256) void k_linear(const float* __restrict__ x,
                                                const _Float16* __restrict__ wh,
                                                const _Float16* __restrict__ wl,
                                                const float* __restrict__ bias,
                                                _Float16* __restrict__ zh,
                                                _Float16* __restrict__ zl) {
    const int tid = threadIdx.x;
    const int w = tid >> 6, lane = tid & 63;
    const int col = lane & 15, kg = lane >> 4;
    const int m0 = blockIdx.x * 64;
    const int e0 = w * 64;

    f32x4 acc[4][4];
    #pragma unroll
    for (int mi = 0; mi < 4; ++mi)
        #pragma unroll
        for (int nj = 0; nj < 4; ++nj) acc[mi][nj] = (f32x4){0.f, 0.f, 0.f, 0.f};

    for (int kc = 0; kc < 8; ++kc) {
        half8 ah[4], al[4], bh[4], bl[4];
        #pragma unroll
        for (int mi = 0; mi < 4; ++mi) {
            const float* p = &x[(size_t)(m0 + mi * 16 + col) * DIM + kc * 32 + kg * 8];
            float4 v0 = *(const float4*)p;
            float4 v1 = *(const float4*)(p + 4);
            float vv[8] = {v0.x, v0.y, v0.z, v0.w, v1.x, v1.y, v1.z, v1.w};
            #pragma unroll
            for (int j = 0; j < 8; ++j) {
                _Float16 h = (_Float16)vv[j];
                ah[mi][j] = h;
                al[mi][j] = (_Float16)(vv[j] - (float)h);
            }
        }
        #pragma unroll
        for (int nj = 0; nj < 4; ++nj) {
            size_t off = (size_t)(e0 + nj * 16 + col) * DIM + kc * 32 + kg * 8;
            bh[nj] = *(const half8*)&wh[off];
            bl[nj] = *(const half8*)&wl[off];
        }
        #pragma unroll
        for (int mi = 0; mi < 4; ++mi)
            #pragma unroll
            for (int nj = 0; nj < 4; ++nj) {
                acc[mi][nj] = __builtin_amdgcn_mfma_f32_16x16x32_f16(ah[mi], bh[nj], acc[mi][nj], 0, 0, 0);
                acc[mi][nj] = __builtin_amdgcn_mfma_f32_16x16x32_f16(ah[mi], bl[nj], acc[mi][nj], 0, 0, 0);
                acc[mi][nj] = __builtin_amdgcn_mfma_f32_16x16x32_f16(al[mi], bh[nj], acc[mi][nj], 0, 0, 0);
            }
    }
    #pragma unroll
    for (int nj = 0; nj < 4; ++nj) {
        int e = e0 + nj * 16 + col;
        float bv = bias[e];
        #pragma unroll
        for (int mi = 0; mi < 4; ++mi)
            #pragma unroll
            for (int r = 0; r < 4; ++r) {
                int m = m0 + mi * 16 + kg * 4 + r;
                float zv = acc[mi][nj][r] + bv;
                _Float16 h = (_Float16)zv;
                zh[(size_t)m * DIM + e] = h;
                zl[(size_t)m * DIM + e] = (_Float16)(zv - (float)h);
            }
    }
}

// ---------------- cb-chunk staging: 128 codes x 64 dims of one array (ch or cl) ----------------
__device__ __forceinline__ void stage_chunk(int c, int split, const _Float16* __restrict__ csrc,
                                            char* smem, int arrOff, int rbase,
                                            int srow, int sch) {
    int t = c >> 2, kc = c & 3;
    int n0 = split * CPS + t * 128;
    char* dst0 = smem + (c & 1) * 32768 + arrOff + rbase * 128;
    const _Float16* g0 = csrc + (size_t)(n0 + rbase + srow) * DIM + kc * 64 + sch * 8;
    #pragma unroll
    for (int j = 0; j < 8; ++j)
        __builtin_amdgcn_global_load_lds(GLOBAL_AS(g0 + (size_t)(j * 8) * DIM),
                                         LDS_AS(dst0 + j * 1024), 16, 0, 0);
}

// ---------------- kernel: fp16x2 MFMA distance argmin; z-fragments register-resident ----------------
// 128 tokens x 128 codes tile; 4 waves (2x2); A (z-high) held in regs for full K=256.
__global__ __launch_bounds__(256, 2) void k_argmin(const _Float16* __restrict__ zh,
                                                   const _Float16* __restrict__ ch,
                                                   const _Float16* __restrict__ cl,
                                                   const float* __restrict__ cnorm,
                                                   float4* __restrict__ cand) {
    __shared__ __align__(16) char smem[65536];   // 2 x (ch 16K + cl 16K)
    const int tid = threadIdx.x;
    const int w = tid >> 6, lane = tid & 63;
    const int wm = w >> 1, wn = w & 1;
    const int col = lane & 15, kg = lane >> 4;
    const int m0 = blockIdx.x * 128;
    const int split = blockIdx.y;
    const int srow = lane >> 3, sch = (lane & 7) ^ srow;
    const _Float16* csrc = (w < 2) ? ch : cl;
    const int arrOff = (w < 2) ? 0 : 16384;
    const int rbase = (w & 1) * 64;

    // A fragments: zh rows for this wave, full K=256 (8 chunks of 32), 128 VGPRs
    half8 ah[8][4];
    #pragma unroll
    for (int kc = 0; kc < 8; ++kc)
        #pragma unroll
        for (int mi = 0; mi < 4; ++mi)
            ah[kc][mi] = *(const half8*)&zh[(size_t)(m0 + wm * 64 + mi * 16 + col) * DIM + kc * 32 + kg * 8];

    float val[16];
    unsigned pidx[8];
    #pragma unroll
    for (int s = 0; s < 16; ++s) val[s] = 3.4e38f;
    #pragma unroll
    for (int s = 0; s < 8; ++s) pidx[s] = 0xFFFFFFFFu;

    f32x4 acc[4][4];
    #pragma unroll
    for (int mi = 0; mi < 4; ++mi)
        #pragma unroll
        for (int nj = 0; nj < 4; ++nj) acc[mi][nj] = (f32x4){0.f, 0.f, 0.f, 0.f};

    stage_chunk(0, split, csrc, smem, arrOff, rbase, srow, sch);
    __syncthreads();

    for (int c = 0; c < 64; ++c) {
        if (c < 63) stage_chunk(c + 1, split, csrc, smem, arrOff, rbase, srow, sch);

        const _Float16* bufh = (const _Float16*)(smem + (c & 1) * 32768);
        const _Float16* bufl = bufh + 8192;
        #pragma unroll
        for (int kk = 0; kk < 2; ++kk) {
            const int cb8 = kk * 4 + kg;
            const int kcA = (c & 3) * 2 + kk;
            #pragma unroll
            for (int nj = 0; nj < 4; ++nj) {
                int r = wn * 64 + nj * 16 + col;
                int off = r * 64 + ((cb8 ^ (r & 7)) << 3);
                half8 bh = *(const half8*)&bufh[off];
                half8 bl = *(const half8*)&bufl[off];
                #pragma unroll
                for (int mi = 0; mi < 4; ++mi) {
                    acc[mi][nj] = __builtin_amdgcn_mfma_f32_16x16x32_f16(ah[kcA][mi], bh, acc[mi][nj], 0, 0, 0);
                    acc[mi][nj] = __builtin_amdgcn_mfma_f32_16x16x32_f16(ah[kcA][mi], bl, acc[mi][nj], 0, 0, 0);
                }
            }
        }
        if ((c & 3) == 3) {
            int t = c >> 2;
            #pragma unroll
            for (int nj = 0; nj < 4; ++nj) {
                int nl = t * 128 + wn * 64 + nj * 16 + col;    // index within split, fits 16 bits
                float cn = cnorm[split * CPS + nl];
                #pragma unroll
                for (int mi = 0; mi < 4; ++mi)
                    #pragma unroll
                    for (int r2 = 0; r2 < 4; ++r2) {
                        float sc = fmaf(-2.0f, acc[mi][nj][r2], cn);
                        int s = mi * 4 + r2;
                        bool b = sc < val[s];
                        unsigned p = pidx[s >> 1];
                        unsigned np = (s & 1) ? ((p & 0x0000FFFFu) | ((unsigned)nl << 16))
                                              : ((p & 0xFFFF0000u) | (unsigned)nl);
                        val[s] = b ? sc : val[s];
                        pidx[s >> 1] = b ? np : p;
                    }
            }
            #pragma unroll
            for (int mi = 0; mi < 4; ++mi)
                #pragma unroll
                for (int nj = 0; nj < 4; ++nj) acc[mi][nj] = (f32x4){0.f, 0.f, 0.f, 0.f};
        }
        __syncthreads();
    }

    // unpack, then top-2 butterfly across the 16 lanes sharing each token row
    float b1[16], b2[16]; int i1[16], i2[16];
    #pragma unroll
    for (int s = 0; s < 16; ++s) {
        unsigned p = pidx[s >> 1];
        int nl = (s & 1) ? (int)(p >> 16) : (int)(p & 0xFFFFu);
        b1[s] = val[s]; i1[s] = split * CPS + nl;
        b2[s] = 3.4e38f; i2[s] = 0x7ffffffe;
    }
    #pragma unroll
    for (int m = 1; m < 16; m <<= 1) {
        #pragma unroll
        for (int s = 0; s < 16; ++s) {
            float p1 = __shfl_xor(b1[s], m); int j1 = __shfl_xor(i1[s], m);
            float p2 = __shfl_xor(b2[s], m); int j2 = __shfl_xor(i2[s], m);
            ins2(p1, j1, b1[s], i1[s], b2[s], i2[s]);
            ins2(p2, j2, b1[s], i1[s], b2[s], i2[s]);
        }
    }
    float4* cbuf = (float4*)smem;   // [128][2]; aliases buf0, dead after last barrier
    if (col == 0) {
        #pragma unroll
        for (int s = 0; s < 16; ++s) {
            int mi = s >> 2, r = s & 3;
            int row = wm * 64 + mi * 16 + kg * 4 + r;
            float4 v; v.x = b1[s]; v.y = __int_as_float(i1[s]); v.z = b2[s]; v.w = __int_as_float(i2[s]);
            cbuf[row * 2 + wn] = v;
        }
    }
    __syncthreads();
    if (tid < 128) {
        float4 a = cbuf[tid * 2 + 0];
        float4 b = cbuf[tid * 2 + 1];
        float v1 = a.x; int j1 = __float_as_int(a.y);
        float v2 = a.z; int j2 = __float_as_int(a.w);
        ins2(b.x, __float_as_int(b.y), v1, j1, v2, j2);
        ins2(b.z, __float_as_int(b.w), v1, j1, v2, j2);
        float4 o; o.x = v1; o.y = __int_as_float(j1); o.z = v2; o.w = __int_as_float(j2);
        cand[(size_t)split * NTOK + m0 + tid] = o;
    }
}

// ---------------- kernel: exact fp32 rescore of all 8 candidates, gather q, loss partials ----------------
__global__ __launch_bounds__(256) void k_finalize(const _Float16* __restrict__ zh,
                                                  const _Float16* __restrict__ zl,
                                                  const float* __restrict__ cb,
                                                  const float* __restrict__ cnorm,
                                                  const float4* __restrict__ cand,
                                                  float* __restrict__ out,
                                                  float* __restrict__ partials) {
    __shared__ float blk[4];
    const int tid = threadIdx.x;
    const int w = tid >> 6, lane = tid & 63;
    const int token = blockIdx.x * 4 + w;

    int ci[8];
    #pragma unroll
    for (int s = 0; s < NSPLIT; ++s) {
        float4 c = cand[(size_t)s * NTOK + token];
        ci[2 * s]     = __float_as_int(c.y);
        ci[2 * s + 1] = __float_as_int(c.w);
    }

    half4 hv = *(const half4*)&zh[(size_t)token * DIM + lane * 4];
    half4 lv = *(const half4*)&zl[(size_t)token * DIM + lane * 4];
    float z0 = (float)hv[0] + (float)lv[0];
    float z1 = (float)hv[1] + (float)lv[1];
    float z2 = (float)hv[2] + (float)lv[2];
    float z3 = (float)hv[3] + (float)lv[3];

    const float4* cb4 = (const float4*)cb;
    float best = 3.4e38f; int bi = 0x7fffffff;
    #pragma unroll
    for (int j = 0; j < 8; ++j) {
        int idx = ci[j];
        float4 e = cb4[(size_t)idx * 64 + lane];
        float d = z0 * e.x + z1 * e.y + z2 * e.z + z3 * e.w;
        #pragma unroll
        for (int m = 32; m; m >>= 1) d += __shfl_xor(d, m);
        float sc = cnorm[idx] - 2.0f * d;
        if (sc < best || (sc == best && idx < bi)) { best = sc; bi = idx; }
    }

    float4 q = cb4[(size_t)bi * 64 + lane];
    *(float4*)&out[(size_t)token * DIM + lane * 4] = q;   // x_recon == q (STE)

    float dx = z0 - q.x, dy = z1 - q.y, dz = z2 - q.z, dw = z3 - q.w;
    float ss = dx*dx + dy*dy + dz*dz + dw*dw;
    #pragma unroll
    for (int m = 32; m; m >>= 1) ss += __shfl_xor(ss, m);
    if (lane == 0) blk[w] = ss;
    __syncthreads();
    if (tid == 0) partials[blockIdx.x] = blk[0] + blk[1] + blk[2] + blk[3];
}

// ---------------- kernel: reduce partials, write both losses ----------------
__global__ __launch_bounds__(256) void k_losses(const float* __restrict__ partials,
                                                float* __restrict__ out) {
    __shared__ float red[256];
    float s = 0.0f;
    for (int i = threadIdx.x; i < NTOK / 4; i += 256) s += partials[i];
    red[threadIdx.x] = s;
    __syncthreads();
    for (int off = 128; off; off >>= 1) {
        if ((int)threadIdx.x < off) red[threadIdx.x] += red[threadIdx.x + off];
        __syncthreads();
    }
    if (threadIdx.x == 0) {
        float l = red[0] / (float)((size_t)NTOK * DIM);
        out[(size_t)NTOK * DIM]     = l;  // dictionary_loss
        out[(size_t)NTOK * DIM + 1] = l;  // commitment_loss
    }
}

extern "C" void kernel_launch(void* const* d_in, const int* in_sizes, int n_in,
                              void* d_out, int out_size, void* d_ws, size_t ws_size,
                              hipStream_t stream) {
    const float* x  = (const float*)d_in[0];
    const float* W  = (const float*)d_in[1];
    const float* b  = (const float*)d_in[2];
    const float* cb = (const float*)d_in[3];
    float* out = (float*)d_out;

    char* ws = (char*)d_ws;
    size_t off = 0;
    _Float16* zh = (_Float16*)(ws + off); off += (size_t)NTOK * DIM * 2;     // 16 MB
    _Float16* zl = (_Float16*)(ws + off); off += (size_t)NTOK * DIM * 2;     // 16 MB
    _Float16* ch = (_Float16*)(ws + off); off += (size_t)KCB * DIM * 2;      // 4 MB
    _Float16* cl = (_Float16*)(ws + off); off += (size_t)KCB * DIM * 2;      // 4 MB
    _Float16* wh = (_Float16*)(ws + off); off += (size_t)DIM * DIM * 2;      // 128 KB
    _Float16* wl = (_Float16*)(ws + off); off += (size_t)DIM * DIM * 2;      // 128 KB
    float* cnorm = (float*)(ws + off);    off += (size_t)KCB * 4;            // 32 KB
    float4* cand = (float4*)(ws + off);   off += (size_t)NSPLIT * NTOK * 16; // 2 MB
    float* parts = (float*)(ws + off);

    k_split<<<dim3(DIM / 4), 256, 0, stream>>>(W, wh, wl, nullptr, DIM);
    k_split<<<dim3(KCB / 4), 256, 0, stream>>>(cb, ch, cl, cnorm, KCB);
    k_linear<<<dim3(NTOK / 64), 256, 0, stream>>>(x, wh, wl, b, zh, zl);
    k_argmin<<<dim3(NTOK / 128, NSPLIT), 256, 0, stream>>>(zh, ch, cl, cnorm, cand);
    k_finalize<<<dim3(NTOK / 4), 256, 0, stream>>>(zh, zl, cb, cnorm, cand, out, parts);
    k_losses<<<1, 256, 0, stream>>>(parts, out);
}

// Round 4
// 565.744 us; speedup vs baseline: 1.2706x; 1.2706x over previous
//
#include <hip/hip_runtime.h>

#define DIM   256
#define KCB   8192
#define NTOK  32768
#define NSPLIT 2
#define CPS   4096      // codes per split

using half8 = __attribute__((ext_vector_type(8))) _Float16;
using half4 = __attribute__((ext_vector_type(4))) _Float16;
using f32x4 = __attribute__((ext_vector_type(4))) float;

#define GLOBAL_AS(p) ((const __attribute__((address_space(1))) void*)(p))
#define LDS_AS(p)    ((__attribute__((address_space(3))) void*)(p))

__device__ __forceinline__ void ins2(float v, int i, float& b1v, int& b1i,
                                     float& b2v, int& b2i) {
    bool bet1 = (v < b1v) || (v == b1v && i < b1i);
    bool bet2 = (v < b2v) || (v == b2v && i < b2i);
    if (bet1) { b2v = b1v; b2i = b1i; b1v = v; b1i = i; }
    else if (bet2) { b2v = v; b2i = i; }
}

// ---------------- split fp32 rows into fp16 hi (+ optional lo, + optional norms) ----------------
__global__ __launch_bounds__(256) void k_split(const float* __restrict__ src,
                                               _Float16* __restrict__ hi,
                                               _Float16* __restrict__ lo,
                                               float* __restrict__ norm, int nrows) {
    int row = (int)((blockIdx.x * blockDim.x + threadIdx.x) >> 6);
    int lane = threadIdx.x & 63;
    if (row >= nrows) return;
    float4 v = *(const float4*)&src[(size_t)row * DIM + lane * 4];
    float vv[4] = {v.x, v.y, v.z, v.w};
    half4 hh, hl;
    #pragma unroll
    for (int j = 0; j < 4; ++j) {
        _Float16 h = (_Float16)vv[j];
        hh[j] = h;
        hl[j] = (_Float16)(vv[j] - (float)h);
    }
    *(half4*)&hi[(size_t)row * DIM + lane * 4] = hh;
    if (lo) *(half4*)&lo[(size_t)row * DIM + lane * 4] = hl;
    if (norm) {
        float s = v.x*v.x + v.y*v.y + v.z*v.z + v.w*v.w;
        #pragma unroll
        for (int m = 32; m; m >>= 1) s += __shfl_xor(s, m);
        if (lane == 0) norm[row] = s;
    }
}

// ---------------- z = x @ W^T + b via fp16x3 MFMA, stored as (zh, zl) ----------------
__global__ __launch_bounds__(256) void k_linear(const float* __restrict__ x,
                                                const _Float16* __restrict__ wh,
                                                const _Float16* __restrict__ wl,
                                                const float* __restrict__ bias,
                                                _Float16* __restrict__ zh,
                                                _Float16* __restrict__ zl) {
    const int tid = threadIdx.x;
    const int w = tid >> 6, lane = tid & 63;
    const int col = lane & 15, kg = lane >> 4;
    const int m0 = blockIdx.x * 64;
    const int e0 = w * 64;

    f32x4 acc[4][4];
    #pragma unroll
    for (int mi = 0; mi < 4; ++mi)
        #pragma unroll
        for (int nj = 0; nj < 4; ++nj) acc[mi][nj] = (f32x4){0.f, 0.f, 0.f, 0.f};

    for (int kc = 0; kc < 8; ++kc) {
        half8 ah[4], al[4], bh[4], bl[4];
        #pragma unroll
        for (int mi = 0; mi < 4; ++mi) {
            const float* p = &x[(size_t)(m0 + mi * 16 + col) * DIM + kc * 32 + kg * 8];
            float4 v0 = *(const float4*)p;
            float4 v1 = *(const float4*)(p + 4);
            float vv[8] = {v0.x, v0.y, v0.z, v0.w, v1.x, v1.y, v1.z, v1.w};
            #pragma unroll
            for (int j = 0; j < 8; ++j) {
                _Float16 h = (_Float16)vv[j];
                ah[mi][j] = h;
                al[mi][j] = (_Float16)(vv[j] - (float)h);
            }
        }
        #pragma unroll
        for (int nj = 0; nj < 4; ++nj) {
            size_t off = (size_t)(e0 + nj * 16 + col) * DIM + kc * 32 + kg * 8;
            bh[nj] = *(const half8*)&wh[off];
            bl[nj] = *(const half8*)&wl[off];
        }
        #pragma unroll
        for (int mi = 0; mi < 4; ++mi)
            #pragma unroll
            for (int nj = 0; nj < 4; ++nj) {
                acc[mi][nj] = __builtin_amdgcn_mfma_f32_16x16x32_f16(ah[mi], bh[nj], acc[mi][nj], 0, 0, 0);
                acc[mi][nj] = __builtin_amdgcn_mfma_f32_16x16x32_f16(ah[mi], bl[nj], acc[mi][nj], 0, 0, 0);
                acc[mi][nj] = __builtin_amdgcn_mfma_f32_16x16x32_f16(al[mi], bh[nj], acc[mi][nj], 0, 0, 0);
            }
    }
    #pragma unroll
    for (int nj = 0; nj < 4; ++nj) {
        int e = e0 + nj * 16 + col;
        float bv = bias[e];
        #pragma unroll
        for (int mi = 0; mi < 4; ++mi)
            #pragma unroll
            for (int r = 0; r < 4; ++r) {
                int m = m0 + mi * 16 + kg * 4 + r;
                float zv = acc[mi][nj][r] + bv;
                _Float16 h = (_Float16)zv;
                zh[(size_t)m * DIM + e] = h;
                zl[(size_t)m * DIM + e] = (_Float16)(zv - (float)h);
            }
    }
}

// ---------------- stage one chunk: 128 codes x 128 dims of ch (32 KB), XOR-swizzled ----------------
__device__ __forceinline__ void stage_chunk(int c, int split, const _Float16* __restrict__ ch,
                                            char* smem, int w, int lane) {
    const int t = c >> 1, kc = c & 1;
    const int n0 = split * CPS + t * 128;
    const int sr = lane >> 4, cp = lane & 15;
    char* dst = smem + (c & 1) * 32768 + (w * 32) * 256;
    #pragma unroll
    for (int j = 0; j < 8; ++j) {
        int row = w * 32 + j * 4 + sr;
        int gc = cp ^ (row & 15);
        const _Float16* g = ch + (size_t)(n0 + row) * DIM + kc * 128 + gc * 8;
        __builtin_amdgcn_global_load_lds(GLOBAL_AS(g), LDS_AS(dst + j * 1024), 16, 0, 0);
    }
}

// ---------------- fp16x1 MFMA distance argmin; zh fragments register-resident ----------------
// 128 tokens x 128 codes tile; 4 waves (2x2); L2-resident ch stream (4 MB total).
__global__ __launch_bounds__(256, 2) void k_argmin(const _Float16* __restrict__ zh,
                                                   const _Float16* __restrict__ ch,
                                                   const float* __restrict__ cnorm,
                                                   float4* __restrict__ cand) {
    __shared__ __align__(16) char smem[65536];   // 2 x 32 KB double buffer
    const int tid = threadIdx.x;
    const int w = tid >> 6, lane = tid & 63;
    const int wm = w >> 1, wn = w & 1;
    const int col = lane & 15, kg = lane >> 4;
    const int m0 = blockIdx.x * 128;
    const int split = blockIdx.y;

    // A fragments: zh rows for this wave, full K=256 (8 chunks of 32), 128 VGPRs
    half8 ah[8][4];
    #pragma unroll
    for (int kc = 0; kc < 8; ++kc)
        #pragma unroll
        for (int mi = 0; mi < 4; ++mi)
            ah[kc][mi] = *(const half8*)&zh[(size_t)(m0 + wm * 64 + mi * 16 + col) * DIM + kc * 32 + kg * 8];

    float val[16];
    unsigned pidx[8];
    #pragma unroll
    for (int s = 0; s < 16; ++s) val[s] = 3.4e38f;
    #pragma unroll
    for (int s = 0; s < 8; ++s) pidx[s] = 0xFFFFFFFFu;

    f32x4 acc[4][4];
    #pragma unroll
    for (int mi = 0; mi < 4; ++mi)
        #pragma unroll
        for (int nj = 0; nj < 4; ++nj) acc[mi][nj] = (f32x4){0.f, 0.f, 0.f, 0.f};

    stage_chunk(0, split, ch, smem, w, lane);
    __syncthreads();

    for (int c = 0; c < 2 * CPS / 128; ++c) {
        if (c < 2 * CPS / 128 - 1) stage_chunk(c + 1, split, ch, smem, w, lane);

        const _Float16* buf = (const _Float16*)(smem + (c & 1) * 32768);
        const int kc = c & 1;
        #pragma unroll
        for (int sub = 0; sub < 4; ++sub) {
            const int kcA = kc * 4 + sub;
            #pragma unroll
            for (int nj = 0; nj < 4; ++nj) {
                int r = wn * 64 + nj * 16 + col;
                int off = r * 128 + (((sub * 4 + kg) ^ (r & 15)) << 3);
                half8 bh = *(const half8*)&buf[off];
                #pragma unroll
                for (int mi = 0; mi < 4; ++mi)
                    acc[mi][nj] = __builtin_amdgcn_mfma_f32_16x16x32_f16(ah[kcA][mi], bh, acc[mi][nj], 0, 0, 0);
            }
        }
        if (kc == 1) {   // tile t = c>>1 complete over K=256: score + reset
            int t = c >> 1;
            #pragma unroll
            for (int nj = 0; nj < 4; ++nj) {
                int nl = t * 128 + wn * 64 + nj * 16 + col;    // < 4096, fits 16 bits
                float cn = cnorm[split * CPS + nl];
                #pragma unroll
                for (int mi = 0; mi < 4; ++mi)
                    #pragma unroll
                    for (int r2 = 0; r2 < 4; ++r2) {
                        float sc = fmaf(-2.0f, acc[mi][nj][r2], cn);
                        int s = mi * 4 + r2;
                        bool b = sc < val[s];
                        unsigned p = pidx[s >> 1];
                        unsigned np = (s & 1) ? ((p & 0x0000FFFFu) | ((unsigned)nl << 16))
                                              : ((p & 0xFFFF0000u) | (unsigned)nl);
                        val[s] = b ? sc : val[s];
                        pidx[s >> 1] = b ? np : p;
                    }
            }
            #pragma unroll
            for (int mi = 0; mi < 4; ++mi)
                #pragma unroll
                for (int nj = 0; nj < 4; ++nj) acc[mi][nj] = (f32x4){0.f, 0.f, 0.f, 0.f};
        }
        __syncthreads();
    }

    // unpack, then top-2 butterfly across the 16 lanes sharing each token row
    float b1[16], b2[16]; int i1[16], i2[16];
    #pragma unroll
    for (int s = 0; s < 16; ++s) {
        unsigned p = pidx[s >> 1];
        int nl = (s & 1) ? (int)(p >> 16) : (int)(p & 0xFFFFu);
        b1[s] = val[s]; i1[s] = split * CPS + nl;
        b2[s] = 3.4e38f; i2[s] = 0x7ffffffe;
    }
    #pragma unroll
    for (int m = 1; m < 16; m <<= 1) {
        #pragma unroll
        for (int s = 0; s < 16; ++s) {
            float p1 = __shfl_xor(b1[s], m); int j1 = __shfl_xor(i1[s], m);
            float p2 = __shfl_xor(b2[s], m); int j2 = __shfl_xor(i2[s], m);
            ins2(p1, j1, b1[s], i1[s], b2[s], i2[s]);
            ins2(p2, j2, b1[s], i1[s], b2[s], i2[s]);
        }
    }
    float4* cbuf = (float4*)smem;   // [128][2]; aliases buf0, dead after last barrier
    if (col == 0) {
        #pragma unroll
        for (int s = 0; s < 16; ++s) {
            int mi = s >> 2, r = s & 3;
            int row = wm * 64 + mi * 16 + kg * 4 + r;
            float4 v; v.x = b1[s]; v.y = __int_as_float(i1[s]); v.z = b2[s]; v.w = __int_as_float(i2[s]);
            cbuf[row * 2 + wn] = v;
        }
    }
    __syncthreads();
    if (tid < 128) {
        float4 a = cbuf[tid * 2 + 0];
        float4 b = cbuf[tid * 2 + 1];
        float v1 = a.x; int j1 = __float_as_int(a.y);
        float v2 = a.z; int j2 = __float_as_int(a.w);
        ins2(b.x, __float_as_int(b.y), v1, j1, v2, j2);
        ins2(b.z, __float_as_int(b.w), v1, j1, v2, j2);
        float4 o; o.x = v1; o.y = __int_as_float(j1); o.z = v2; o.w = __int_as_float(j2);
        cand[(size_t)split * NTOK + m0 + tid] = o;
    }
}

// ---------------- exact fp32 rescore of 4 candidates, gather q, loss partials ----------------
__global__ __launch_bounds__(256) void k_finalize(const _Float16* __restrict__ zh,
                                                  const _Float16* __restrict__ zl,
                                                  const float* __restrict__ cb,
                                                  const float* __restrict__ cnorm,
                                                  const float4* __restrict__ cand,
                                                  float* __restrict__ out,
                                                  float* __restrict__ partials) {
    __shared__ float blk[4];
    const int tid = threadIdx.x;
    const int w = tid >> 6, lane = tid & 63;
    const int token = blockIdx.x * 4 + w;

    int ci[4];
    #pragma unroll
    for (int s = 0; s < NSPLIT; ++s) {
        float4 c = cand[(size_t)s * NTOK + token];
        ci[2 * s]     = __float_as_int(c.y);
        ci[2 * s + 1] = __float_as_int(c.w);
    }

    half4 hv = *(const half4*)&zh[(size_t)token * DIM + lane * 4];
    half4 lv = *(const half4*)&zl[(size_t)token * DIM + lane * 4];
    float z0 = (float)hv[0] + (float)lv[0];
    float z1 = (float)hv[1] + (float)lv[1];
    float z2 = (float)hv[2] + (float)lv[2];
    float z3 = (float)hv[3] + (float)lv[3];

    const float4* cb4 = (const float4*)cb;
    float best = 3.4e38f; int bi = 0x7fffffff;
    #pragma unroll
    for (int j = 0; j < 2 * NSPLIT; ++j) {
        int idx = ci[j];
        float4 e = cb4[(size_t)idx * 64 + lane];
        float d = z0 * e.x + z1 * e.y + z2 * e.z + z3 * e.w;
        #pragma unroll
        for (int m = 32; m; m >>= 1) d += __shfl_xor(d, m);
        float sc = cnorm[idx] - 2.0f * d;
        if (sc < best || (sc == best && idx < bi)) { best = sc; bi = idx; }
    }

    float4 q = cb4[(size_t)bi * 64 + lane];
    *(float4*)&out[(size_t)token * DIM + lane * 4] = q;   // x_recon == q (STE)

    float dx = z0 - q.x, dy = z1 - q.y, dz = z2 - q.z, dw = z3 - q.w;
    float ss = dx*dx + dy*dy + dz*dz + dw*dw;
    #pragma unroll
    for (int m = 32; m; m >>= 1) ss += __shfl_xor(ss, m);
    if (lane == 0) blk[w] = ss;
    __syncthreads();
    if (tid == 0) partials[blockIdx.x] = blk[0] + blk[1] + blk[2] + blk[3];
}

// ---------------- reduce partials, write both losses ----------------
__global__ __launch_bounds__(256) void k_losses(const float* __restrict__ partials,
                                                float* __restrict__ out) {
    __shared__ float red[256];
    float s = 0.0f;
    for (int i = threadIdx.x; i < NTOK / 4; i += 256) s += partials[i];
    red[threadIdx.x] = s;
    __syncthreads();
    for (int off = 128; off; off >>= 1) {
        if ((int)threadIdx.x < off) red[threadIdx.x] += red[threadIdx.x + off];
        __syncthreads();
    }
    if (threadIdx.x == 0) {
        float l = red[0] / (float)((size_t)NTOK * DIM);
        out[(size_t)NTOK * DIM]     = l;  // dictionary_loss
        out[(size_t)NTOK * DIM + 1] = l;  // commitment_loss
    }
}

extern "C" void kernel_launch(void* const* d_in, const int* in_sizes, int n_in,
                              void* d_out, int out_size, void* d_ws, size_t ws_size,
                              hipStream_t stream) {
    const float* x  = (const float*)d_in[0];
    const float* W  = (const float*)d_in[1];
    const float* b  = (const float*)d_in[2];
    const float* cb = (const float*)d_in[3];
    float* out = (float*)d_out;

    char* ws = (char*)d_ws;
    size_t off = 0;
    _Float16* zh = (_Float16*)(ws + off); off += (size_t)NTOK * DIM * 2;     // 16 MB
    _Float16* zl = (_Float16*)(ws + off); off += (size_t)NTOK * DIM * 2;     // 16 MB
    _Float16* ch = (_Float16*)(ws + off); off += (size_t)KCB * DIM * 2;      // 4 MB
    _Float16* wh = (_Float16*)(ws + off); off += (size_t)DIM * DIM * 2;      // 128 KB
    _Float16* wl = (_Float16*)(ws + off); off += (size_t)DIM * DIM * 2;      // 128 KB
    float* cnorm = (float*)(ws + off);    off += (size_t)KCB * 4;            // 32 KB
    float4* cand = (float4*)(ws + off);   off += (size_t)NSPLIT * NTOK * 16; // 1 MB
    float* parts = (float*)(ws + off);

    k_split<<<dim3(DIM / 4), 256, 0, stream>>>(W, wh, wl, nullptr, DIM);
    k_split<<<dim3(KCB / 4), 256, 0, stream>>>(cb, ch, nullptr, cnorm, KCB);
    k_linear<<<dim3(NTOK / 64), 256, 0, stream>>>(x, wh, wl, b, zh, zl);
    k_argmin<<<dim3(NTOK / 128, NSPLIT), 256, 0, stream>>>(zh, ch, cnorm, cand);
    k_finalize<<<dim3(NTOK / 4), 256, 0, stream>>>(zh, zl, cb, cnorm, cand, out, parts);
    k_losses<<<1, 256, 0, stream>>>(parts, out);
}

// Round 5
// 563.021 us; speedup vs baseline: 1.2768x; 1.0048x over previous
//
#include <hip/hip_runtime.h>

#define DIM   256
#define KCB   8192
#define NTOK  32768
#define NSPLIT 2
#define CPS   4096      // codes per split

using half8 = __attribute__((ext_vector_type(8))) _Float16;
using half4 = __attribute__((ext_vector_type(4))) _Float16;
using f32x4 = __attribute__((ext_vector_type(4))) float;

#define GLOBAL_AS(p) ((const __attribute__((address_space(1))) void*)(p))
#define LDS_AS(p)    ((__attribute__((address_space(3))) void*)(p))

__device__ __forceinline__ void ins2(float v, int i, float& b1v, int& b1i,
                                     float& b2v, int& b2i) {
    bool bet1 = (v < b1v) || (v == b1v && i < b1i);
    bool bet2 = (v < b2v) || (v == b2v && i < b2i);
    if (bet1) { b2v = b1v; b2i = b1i; b1v = v; b1i = i; }
    else if (bet2) { b2v = v; b2i = i; }
}

// ---------------- split fp32 rows into fp16 hi (+ optional lo, + optional norms) ----------------
__global__ __launch_bounds__(256) void k_split(const float* __restrict__ src,
                                               _Float16* __restrict__ hi,
                                               _Float16* __restrict__ lo,
                                               float* __restrict__ norm, int nrows) {
    int row = (int)((blockIdx.x * blockDim.x + threadIdx.x) >> 6);
    int lane = threadIdx.x & 63;
    if (row >= nrows) return;
    float4 v = *(const float4*)&src[(size_t)row * DIM + lane * 4];
    float vv[4] = {v.x, v.y, v.z, v.w};
    half4 hh, hl;
    #pragma unroll
    for (int j = 0; j < 4; ++j) {
        _Float16 h = (_Float16)vv[j];
        hh[j] = h;
        hl[j] = (_Float16)(vv[j] - (float)h);
    }
    *(half4*)&hi[(size_t)row * DIM + lane * 4] = hh;
    if (lo) *(half4*)&lo[(size_t)row * DIM + lane * 4] = hl;
    if (norm) {
        float s = v.x*v.x + v.y*v.y + v.z*v.z + v.w*v.w;
        #pragma unroll
        for (int m = 32; m; m >>= 1) s += __shfl_xor(s, m);
        if (lane == 0) norm[row] = s;
    }
}

// ---------------- z = x @ W^T + b via fp16x3 MFMA, stored as (zh, zl) ----------------
__global__ __launch_bounds__(256) void k_linear(const float* __restrict__ x,
                                                const _Float16* __restrict__ wh,
                                                const _Float16* __restrict__ wl,
                                                const float* __restrict__ bias,
                                                _Float16* __restrict__ zh,
                                                _Float16* __restrict__ zl) {
    const int tid = threadIdx.x;
    const int w = tid >> 6, lane = tid & 63;
    const int col = lane & 15, kg = lane >> 4;
    const int m0 = blockIdx.x * 64;
    const int e0 = w * 64;

    f32x4 acc[4][4];
    #pragma unroll
    for (int mi = 0; mi < 4; ++mi)
        #pragma unroll
        for (int nj = 0; nj < 4; ++nj) acc[mi][nj] = (f32x4){0.f, 0.f, 0.f, 0.f};

    for (int kc = 0; kc < 8; ++kc) {
        half8 ah[4], al[4], bh[4], bl[4];
        #pragma unroll
        for (int mi = 0; mi < 4; ++mi) {
            const float* p = &x[(size_t)(m0 + mi * 16 + col) * DIM + kc * 32 + kg * 8];
            float4 v0 = *(const float4*)p;
            float4 v1 = *(const float4*)(p + 4);
            float vv[8] = {v0.x, v0.y, v0.z, v0.w, v1.x, v1.y, v1.z, v1.w};
            #pragma unroll
            for (int j = 0; j < 8; ++j) {
                _Float16 h = (_Float16)vv[j];
                ah[mi][j] = h;
                al[mi][j] = (_Float16)(vv[j] - (float)h);
            }
        }
        #pragma unroll
        for (int nj = 0; nj < 4; ++nj) {
            size_t off = (size_t)(e0 + nj * 16 + col) * DIM + kc * 32 + kg * 8;
            bh[nj] = *(const half8*)&wh[off];
            bl[nj] = *(const half8*)&wl[off];
        }
        #pragma unroll
        for (int mi = 0; mi < 4; ++mi)
            #pragma unroll
            for (int nj = 0; nj < 4; ++nj) {
                acc[mi][nj] = __builtin_amdgcn_mfma_f32_16x16x32_f16(ah[mi], bh[nj], acc[mi][nj], 0, 0, 0);
                acc[mi][nj] = __builtin_amdgcn_mfma_f32_16x16x32_f16(ah[mi], bl[nj], acc[mi][nj], 0, 0, 0);
                acc[mi][nj] = __builtin_amdgcn_mfma_f32_16x16x32_f16(al[mi], bh[nj], acc[mi][nj], 0, 0, 0);
            }
    }
    #pragma unroll
    for (int nj = 0; nj < 4; ++nj) {
        int e = e0 + nj * 16 + col;
        float bv = bias[e];
        #pragma unroll
        for (int mi = 0; mi < 4; ++mi)
            #pragma unroll
            for (int r = 0; r < 4; ++r) {
                int m = m0 + mi * 16 + kg * 4 + r;
                float zv = acc[mi][nj][r] + bv;
                _Float16 h = (_Float16)zv;
                zh[(size_t)m * DIM + e] = h;
                zl[(size_t)m * DIM + e] = (_Float16)(zv - (float)h);
            }
    }
}

// ---------------- stage one chunk: 128 codes x 128 dims of ch (32 KB), XOR-swizzled ----------------
__device__ __forceinline__ void stage_chunk(int c, int split, const _Float16* __restrict__ ch,
                                            char* smem, int w, int lane) {
    const int t = c >> 1, kc = c & 1;
    const int n0 = split * CPS + t * 128;
    const int sr = lane >> 4, cp = lane & 15;
    char* dst = smem + (c & 1) * 32768 + (w * 32) * 256;
    #pragma unroll
    for (int j = 0; j < 8; ++j) {
        int row = w * 32 + j * 4 + sr;
        int gc = cp ^ (row & 15);
        const _Float16* g = ch + (size_t)(n0 + row) * DIM + kc * 128 + gc * 8;
        __builtin_amdgcn_global_load_lds(GLOBAL_AS(g), LDS_AS(dst + j * 1024), 16, 0, 0);
    }
}

// ---------------- fp16x1 MFMA distance argmin; zh fragments register-resident ----------------
// 128 tokens x 128 codes tile; 4 waves (2x2).
// 1D grid, split = blockIdx.x & 1: with round-robin workgroup->XCD placement (flat id % 8),
// every XCD hosts blocks of ONE split only -> ch footprint 2 MB per XCD L2 (L2-resident).
__global__ __launch_bounds__(256, 2) void k_argmin(const _Float16* __restrict__ zh,
                                                   const _Float16* __restrict__ ch,
                                                   const float* __restrict__ cnorm,
                                                   float4* __restrict__ cand) {
    __shared__ __align__(16) char smem[65536];   // 2 x 32 KB double buffer
    const int tid = threadIdx.x;
    const int w = tid >> 6, lane = tid & 63;
    const int wm = w >> 1, wn = w & 1;
    const int col = lane & 15, kg = lane >> 4;
    const int split = blockIdx.x & 1;            // constant per XCD under %8 placement
    const int m0 = (blockIdx.x >> 1) * 128;

    // A fragments: zh rows for this wave, full K=256 (8 chunks of 32), 128 VGPRs
    half8 ah[8][4];
    #pragma unroll
    for (int kc = 0; kc < 8; ++kc)
        #pragma unroll
        for (int mi = 0; mi < 4; ++mi)
            ah[kc][mi] = *(const half8*)&zh[(size_t)(m0 + wm * 64 + mi * 16 + col) * DIM + kc * 32 + kg * 8];

    float val[16];
    unsigned pidx[8];
    #pragma unroll
    for (int s = 0; s < 16; ++s) val[s] = 3.4e38f;
    #pragma unroll
    for (int s = 0; s < 8; ++s) pidx[s] = 0xFFFFFFFFu;

    f32x4 acc[4][4];
    #pragma unroll
    for (int mi = 0; mi < 4; ++mi)
        #pragma unroll
        for (int nj = 0; nj < 4; ++nj) acc[mi][nj] = (f32x4){0.f, 0.f, 0.f, 0.f};

    stage_chunk(0, split, ch, smem, w, lane);
    __syncthreads();

    for (int c = 0; c < 2 * CPS / 128; ++c) {
        if (c < 2 * CPS / 128 - 1) stage_chunk(c + 1, split, ch, smem, w, lane);

        const _Float16* buf = (const _Float16*)(smem + (c & 1) * 32768);
        const int kc = c & 1;
        #pragma unroll
        for (int sub = 0; sub < 4; ++sub) {
            const int kcA = kc * 4 + sub;
            #pragma unroll
            for (int nj = 0; nj < 4; ++nj) {
                int r = wn * 64 + nj * 16 + col;
                int off = r * 128 + (((sub * 4 + kg) ^ (r & 15)) << 3);
                half8 bh = *(const half8*)&buf[off];
                #pragma unroll
                for (int mi = 0; mi < 4; ++mi)
                    acc[mi][nj] = __builtin_amdgcn_mfma_f32_16x16x32_f16(ah[kcA][mi], bh, acc[mi][nj], 0, 0, 0);
            }
        }
        if (kc == 1) {   // tile t = c>>1 complete over K=256: score + reset
            int t = c >> 1;
            #pragma unroll
            for (int nj = 0; nj < 4; ++nj) {
                int nl = t * 128 + wn * 64 + nj * 16 + col;    // < 4096, fits 16 bits
                float cn = cnorm[split * CPS + nl];
                #pragma unroll
                for (int mi = 0; mi < 4; ++mi)
                    #pragma unroll
                    for (int r2 = 0; r2 < 4; ++r2) {
                        float sc = fmaf(-2.0f, acc[mi][nj][r2], cn);
                        int s = mi * 4 + r2;
                        bool b = sc < val[s];
                        unsigned p = pidx[s >> 1];
                        unsigned np = (s & 1) ? ((p & 0x0000FFFFu) | ((unsigned)nl << 16))
                                              : ((p & 0xFFFF0000u) | (unsigned)nl);
                        val[s] = b ? sc : val[s];
                        pidx[s >> 1] = b ? np : p;
                    }
            }
            #pragma unroll
            for (int mi = 0; mi < 4; ++mi)
                #pragma unroll
                for (int nj = 0; nj < 4; ++nj) acc[mi][nj] = (f32x4){0.f, 0.f, 0.f, 0.f};
        }
        __syncthreads();
    }

    // unpack, then top-2 butterfly across the 16 lanes sharing each token row
    float b1[16], b2[16]; int i1[16], i2[16];
    #pragma unroll
    for (int s = 0; s < 16; ++s) {
        unsigned p = pidx[s >> 1];
        int nl = (s & 1) ? (int)(p >> 16) : (int)(p & 0xFFFFu);
        b1[s] = val[s]; i1[s] = split * CPS + nl;
        b2[s] = 3.4e38f; i2[s] = 0x7ffffffe;
    }
    #pragma unroll
    for (int m = 1; m < 16; m <<= 1) {
        #pragma unroll
        for (int s = 0; s < 16; ++s) {
            float p1 = __shfl_xor(b1[s], m); int j1 = __shfl_xor(i1[s], m);
            float p2 = __shfl_xor(b2[s], m); int j2 = __shfl_xor(i2[s], m);
            ins2(p1, j1, b1[s], i1[s], b2[s], i2[s]);
            ins2(p2, j2, b1[s], i1[s], b2[s], i2[s]);
        }
    }
    float4* cbuf = (float4*)smem;   // [128][2]; aliases buf0, dead after last barrier
    if (col == 0) {
        #pragma unroll
        for (int s = 0; s < 16; ++s) {
            int mi = s >> 2, r = s & 3;
            int row = wm * 64 + mi * 16 + kg * 4 + r;
            float4 v; v.x = b1[s]; v.y = __int_as_float(i1[s]); v.z = b2[s]; v.w = __int_as_float(i2[s]);
            cbuf[row * 2 + wn] = v;
        }
    }
    __syncthreads();
    if (tid < 128) {
        float4 a = cbuf[tid * 2 + 0];
        float4 b = cbuf[tid * 2 + 1];
        float v1 = a.x; int j1 = __float_as_int(a.y);
        float v2 = a.z; int j2 = __float_as_int(a.w);
        ins2(b.x, __float_as_int(b.y), v1, j1, v2, j2);
        ins2(b.z, __float_as_int(b.w), v1, j1, v2, j2);
        float4 o; o.x = v1; o.y = __int_as_float(j1); o.z = v2; o.w = __int_as_float(j2);
        cand[(size_t)split * NTOK + m0 + tid] = o;
    }
}

// ---------------- exact fp32 rescore of 4 candidates, gather q, loss partials ----------------
__global__ __launch_bounds__(256) void k_finalize(const _Float16* __restrict__ zh,
                                                  const _Float16* __restrict__ zl,
                                                  const float* __restrict__ cb,
                                                  const float* __restrict__ cnorm,
                                                  const float4* __restrict__ cand,
                                                  float* __restrict__ out,
                                                  float* __restrict__ partials) {
    __shared__ float blk[4];
    const int tid = threadIdx.x;
    const int w = tid >> 6, lane = tid & 63;
    const int token = blockIdx.x * 4 + w;

    int ci[4];
    #pragma unroll
    for (int s = 0; s < NSPLIT; ++s) {
        float4 c = cand[(size_t)s * NTOK + token];
        ci[2 * s]     = __float_as_int(c.y);
        ci[2 * s + 1] = __float_as_int(c.w);
    }

    half4 hv = *(const half4*)&zh[(size_t)token * DIM + lane * 4];
    half4 lv = *(const half4*)&zl[(size_t)token * DIM + lane * 4];
    float z0 = (float)hv[0] + (float)lv[0];
    float z1 = (float)hv[1] + (float)lv[1];
    float z2 = (float)hv[2] + (float)lv[2];
    float z3 = (float)hv[3] + (float)lv[3];

    const float4* cb4 = (const float4*)cb;
    float best = 3.4e38f; int bi = 0x7fffffff;
    #pragma unroll
    for (int j = 0; j < 2 * NSPLIT; ++j) {
        int idx = ci[j];
        float4 e = cb4[(size_t)idx * 64 + lane];
        float d = z0 * e.x + z1 * e.y + z2 * e.z + z3 * e.w;
        #pragma unroll
        for (int m = 32; m; m >>= 1) d += __shfl_xor(d, m);
        float sc = cnorm[idx] - 2.0f * d;
        if (sc < best || (sc == best && idx < bi)) { best = sc; bi = idx; }
    }

    float4 q = cb4[(size_t)bi * 64 + lane];
    *(float4*)&out[(size_t)token * DIM + lane * 4] = q;   // x_recon == q (STE)

    float dx = z0 - q.x, dy = z1 - q.y, dz = z2 - q.z, dw = z3 - q.w;
    float ss = dx*dx + dy*dy + dz*dz + dw*dw;
    #pragma unroll
    for (int m = 32; m; m >>= 1) ss += __shfl_xor(ss, m);
    if (lane == 0) blk[w] = ss;
    __syncthreads();
    if (tid == 0) partials[blockIdx.x] = blk[0] + blk[1] + blk[2] + blk[3];
}

// ---------------- reduce partials, write both losses ----------------
__global__ __launch_bounds__(256) void k_losses(const float* __restrict__ partials,
                                                float* __restrict__ out) {
    __shared__ float red[256];
    float s = 0.0f;
    for (int i = threadIdx.x; i < NTOK / 4; i += 256) s += partials[i];
    red[threadIdx.x] = s;
    __syncthreads();
    for (int off = 128; off; off >>= 1) {
        if ((int)threadIdx.x < off) red[threadIdx.x] += red[threadIdx.x + off];
        __syncthreads();
    }
    if (threadIdx.x == 0) {
        float l = red[0] / (float)((size_t)NTOK * DIM);
        out[(size_t)NTOK * DIM]     = l;  // dictionary_loss
        out[(size_t)NTOK * DIM + 1] = l;  // commitment_loss
    }
}

extern "C" void kernel_launch(void* const* d_in, const int* in_sizes, int n_in,
                              void* d_out, int out_size, void* d_ws, size_t ws_size,
                              hipStream_t stream) {
    const float* x  = (const float*)d_in[0];
    const float* W  = (const float*)d_in[1];
    const float* b  = (const float*)d_in[2];
    const float* cb = (const float*)d_in[3];
    float* out = (float*)d_out;

    char* ws = (char*)d_ws;
    size_t off = 0;
    _Float16* zh = (_Float16*)(ws + off); off += (size_t)NTOK * DIM * 2;     // 16 MB
    _Float16* zl = (_Float16*)(ws + off); off += (size_t)NTOK * DIM * 2;     // 16 MB
    _Float16* ch = (_Float16*)(ws + off); off += (size_t)KCB * DIM * 2;      // 4 MB
    _Float16* wh = (_Float16*)(ws + off); off += (size_t)DIM * DIM * 2;      // 128 KB
    _Float16* wl = (_Float16*)(ws + off); off += (size_t)DIM * DIM * 2;      // 128 KB
    float* cnorm = (float*)(ws + off);    off += (size_t)KCB * 4;            // 32 KB
    float4* cand = (float4*)(ws + off);   off += (size_t)NSPLIT * NTOK * 16; // 1 MB
    float* parts = (float*)(ws + off);

    k_split<<<dim3(DIM / 4), 256, 0, stream>>>(W, wh, wl, nullptr, DIM);
    k_split<<<dim3(KCB / 4), 256, 0, stream>>>(cb, ch, nullptr, cnorm, KCB);
    k_linear<<<dim3(NTOK / 64), 256, 0, stream>>>(x, wh, wl, b, zh, zl);
    k_argmin<<<dim3(NTOK / 128 * NSPLIT), 256, 0, stream>>>(zh, ch, cnorm, cand);
    k_finalize<<<dim3(NTOK / 4), 256, 0, stream>>>(zh, zl, cb, cnorm, cand, out, parts);
    k_losses<<<1, 256, 0, stream>>>(parts, out);
}